// Round 9
// baseline (590.131 us; speedup 1.0000x reference)
//
#include <hip/hip_runtime.h>
#include <hip/hip_fp16.h>

// Problem constants (fixed by setup_inputs)
#define HW_N 4096   // 64*64 spatial positions
#define C_IN 512    // channels
#define C_Q  64     // query/key channels
#define NB   4      // batch
#define M_Y  640    // Cq + Cq + C stacked output rows
#define M_YP 768    // M_Y padded to a multiple of 256 (rows 640-767 are zero)
#define LOG2E 1.4426950408889634f

typedef __attribute__((ext_vector_type(8))) short short8;
typedef __attribute__((ext_vector_type(4))) short short4v;
typedef __attribute__((ext_vector_type(4))) float float4v;
typedef unsigned short ushort_t;

__device__ __forceinline__ ushort_t f2h(float x) {
    return __half_as_ushort(__float2half(x));  // RNE
}
__device__ __forceinline__ float h2f(ushort_t h) {
    return __half2float(__ushort_as_half(h));
}
__device__ __forceinline__ void gl2lds16(const ushort_t* g, ushort_t* l) {
    __builtin_amdgcn_global_load_lds(
        (const __attribute__((address_space(1))) unsigned int*)g,
        (__attribute__((address_space(3))) unsigned int*)l, 16, 0, 0);
}

// ---------------------------------------------------------------------------
// split stacked W = [Wq;Wk;Wv;0-pad] (768x512 fp32) -> fp16 hi/lo
// ---------------------------------------------------------------------------
__global__ __launch_bounds__(256) void split_w(const float* __restrict__ Wq,
                                               const float* __restrict__ Wk,
                                               const float* __restrict__ Wv,
                                               ushort_t* __restrict__ Wh,
                                               ushort_t* __restrict__ Wl) {
    int idx = (blockIdx.x * 256 + threadIdx.x) * 4;
#pragma unroll
    for (int e = 0; e < 4; e++) {
        int i = idx + e;
        int m = i >> 9, k = i & 511;
        float v = (m < C_Q) ? Wq[m * C_IN + k]
                 : (m < 2 * C_Q) ? Wk[(m - C_Q) * C_IN + k]
                 : (m < M_Y) ? Wv[(size_t)(m - 2 * C_Q) * C_IN + k]
                 : 0.f;                              // zero pad rows 640-767
        ushort_t h = f2h(v);
        Wh[i] = h;
        Wl[i] = f2h(v - h2f(h));
    }
}

// zero the whole output tensor (out accumulates via fp32 atomics in feat8)
__global__ __launch_bounds__(256) void zero_out(float4* __restrict__ p, int n4) {
    int i = blockIdx.x * 256 + threadIdx.x;
    if (i < n4) p[i] = (float4){0.f, 0.f, 0.f, 0.f};
}

// ---------------------------------------------------------------------------
// transpose + split: x [512][4096] fp32 -> xT hi/lo [4096][512] fp16
// blockIdx.z selects the batch.  Also zeroes this batch's D[4096].
// ---------------------------------------------------------------------------
__global__ __launch_bounds__(256) void split_x(const float* __restrict__ x,
                                               ushort_t* __restrict__ xTh,
                                               ushort_t* __restrict__ xTl,
                                               float* __restrict__ D) {
    const size_t bz = blockIdx.z;
    x   += bz * ((size_t)C_IN * HW_N);
    xTh += bz * ((size_t)HW_N * C_IN);
    xTl += bz * ((size_t)HW_N * C_IN);
    D   += bz * HW_N;

    if (blockIdx.y == 0 && blockIdx.x < 16) D[blockIdx.x * 256 + threadIdx.x] = 0.f;

    __shared__ float tile[64][65];
    const int n0 = blockIdx.x * 64, k0 = blockIdx.y * 64;
    const int t = threadIdx.x;
#pragma unroll
    for (int it = 0; it < 4; it++) {
        int e = t + it * 256;
        int r = e >> 4, c4 = (e & 15) << 2;
        float4 v = *(const float4*)(x + (size_t)(k0 + r) * HW_N + n0 + c4);
        tile[r][c4 + 0] = v.x; tile[r][c4 + 1] = v.y;
        tile[r][c4 + 2] = v.z; tile[r][c4 + 3] = v.w;
    }
    __syncthreads();
    const int rr = t >> 2, kq = (t & 3) << 4;
    ushort_t h[16], l[16];
#pragma unroll
    for (int j = 0; j < 16; j++) {
        float v = tile[kq + j][rr];
        h[j] = f2h(v);
        l[j] = f2h(v - h2f(h[j]));
    }
    size_t o = (size_t)(n0 + rr) * C_IN + k0 + kq;
    *(uint4*)(xTh + o) = *(uint4*)h;
    *(uint4*)(xTh + o + 8) = *(uint4*)(h + 8);
    *(uint4*)(xTl + o) = *(uint4*)l;
    *(uint4*)(xTl + o + 8) = *(uint4*)(l + 8);
}

// ---------------------------------------------------------------------------
// Y = W*x + b GEMM: 256m x 256n tile, 512 threads = 8 waves (4m x 2n),
// wave-tile 64x128 (acc[4][8]).  W padded to 768 rows; epilogue guards
// m<640.  LDS 128 KB (1 block/CU, 2 waves/SIMD), grid (16, 3, NB).
// Double-buffered, ONE barrier per k-step, next tile's gl2lds flies over
// the MFMA section.  Pre-swizzled global column -> 0 bank conflicts.
// ---------------------------------------------------------------------------
__global__ __launch_bounds__(512, 2) void ygemm(
    const ushort_t* __restrict__ Ah, const ushort_t* __restrict__ Al,
    const ushort_t* __restrict__ Bh, const ushort_t* __restrict__ Bl,
    const float* __restrict__ bq, const float* __restrict__ bk,
    const float* __restrict__ bv,
    ushort_t* __restrict__ qkTh, ushort_t* __restrict__ qkTl,
    ushort_t* __restrict__ Vh, ushort_t* __restrict__ Vl) {
    const size_t bz = blockIdx.z;
    Bh   += bz * ((size_t)HW_N * C_IN);
    Bl   += bz * ((size_t)HW_N * C_IN);
    qkTh += bz * ((size_t)HW_N * 2 * C_Q);
    qkTl += bz * ((size_t)HW_N * 2 * C_Q);
    Vh   += bz * ((size_t)C_IN * HW_N);
    Vl   += bz * ((size_t)C_IN * HW_N);

    __shared__ ushort_t sAh[2][256 * 32];
    __shared__ ushort_t sAl[2][256 * 32];
    __shared__ ushort_t sBh[2][256 * 32];
    __shared__ ushort_t sBl[2][256 * 32];

    const int tid = threadIdx.x, w = tid >> 6, lane = tid & 63;
    const int quad = lane >> 4, lr = lane & 15;
    const int m0 = blockIdx.y * 256, n0 = blockIdx.x * 256;

    // staging: wave pair (w>>1) owns one of {Ah,Al,Bh,Bl}; (w&1) selects the
    // 128-row half; 8 chunks of 16 rows x 64B each.
    const int mat = w >> 1, half = w & 1;
    const ushort_t* src;
    ushort_t* dst0;
    int rowBase;
    if (mat == 0)      { src = Ah; dst0 = sAh[0]; rowBase = m0; }
    else if (mat == 1) { src = Al; dst0 = sAl[0]; rowBase = m0; }
    else if (mat == 2) { src = Bh; dst0 = sBh[0]; rowBase = n0; }
    else               { src = Bl; dst0 = sBl[0]; rowBase = n0; }
    const int cr = lane >> 2, uv = lane & 3;
    const int kcol = (uv ^ ((cr >> 1) & 3)) << 3;   // pre-swizzled 16B k-unit
    const ushort_t* gk = src + (size_t)(rowBase + half * 128 + cr) * C_IN + kcol;
    const int cOfs = half * 8;                       // chunk index base

    const int wm = (w & 3) * 64, wn = (w >> 2) * 128;
    const int up = (quad ^ ((lr >> 1) & 3)) << 3;   // read-side swizzle

    float4v acc[4][8];
#pragma unroll
    for (int i = 0; i < 4; i++)
#pragma unroll
        for (int j = 0; j < 8; j++) acc[i][j] = (float4v){0.f, 0.f, 0.f, 0.f};

    // prologue: stage k-step 0 into buf 0
#pragma unroll
    for (int c = 0; c < 8; c++)
        gl2lds16(gk + (size_t)(c * 16) * C_IN, dst0 + (cOfs + c) * 512);
    __syncthreads();

    const int NSTEP = C_IN / 32;    // 16
    for (int it = 0; it < NSTEP; ++it) {
        const int cur = it & 1, nxt = cur ^ 1;

        // issue next k-step's loads first — they fly over the MFMA section
        if (it + 1 < NSTEP) {
            ushort_t* db = dst0 + nxt * (256 * 32);
#pragma unroll
            for (int c = 0; c < 8; c++)
                gl2lds16(gk + (size_t)(c * 16) * C_IN + (it + 1) * 32,
                         db + (cOfs + c) * 512);
        }

        // B fragments upfront (reused by all 4 i); A per-i like feat
        short8 bh[8], bl[8];
#pragma unroll
        for (int j = 0; j < 8; j++) {
            const int row = wn + j * 16 + lr;
            bh[j] = *(const short8*)&sBh[cur][row * 32 + up];
            bl[j] = *(const short8*)&sBl[cur][row * 32 + up];
        }
#pragma unroll
        for (int i = 0; i < 4; i++) {
            const int row = wm + i * 16 + lr;
            short8 ah = *(const short8*)&sAh[cur][row * 32 + up];
            short8 al = *(const short8*)&sAl[cur][row * 32 + up];
#pragma unroll
            for (int j = 0; j < 8; j++)
                acc[i][j] = __builtin_amdgcn_mfma_f32_16x16x32_f16(ah, bh[j], acc[i][j], 0, 0, 0);
#pragma unroll
            for (int j = 0; j < 8; j++)
                acc[i][j] = __builtin_amdgcn_mfma_f32_16x16x32_f16(ah, bl[j], acc[i][j], 0, 0, 0);
#pragma unroll
            for (int j = 0; j < 8; j++)
                acc[i][j] = __builtin_amdgcn_mfma_f32_16x16x32_f16(al, bh[j], acc[i][j], 0, 0, 0);
        }
        __syncthreads();  // drains nxt's gl2lds (flew over MFMA); orders WAR
    }

    // epilogue: +bias, fp16 hi/lo split; m<128 -> qkT (transposed), else V;
    // padded rows (m >= 640) skipped.
#pragma unroll
    for (int i = 0; i < 4; i++)
#pragma unroll
        for (int j = 0; j < 8; j++)
#pragma unroll
            for (int r = 0; r < 4; r++) {
                const int m = m0 + wm + i * 16 + quad * 4 + r;
                if (m >= M_Y) continue;
                const int n = n0 + wn + j * 16 + lr;
                float bi = (m < C_Q) ? bq[m]
                          : (m < 2 * C_Q) ? bk[m - C_Q] : bv[m - 2 * C_Q];
                float v = acc[i][j][r] + bi;
                ushort_t h = f2h(v);
                ushort_t lo = f2h(v - h2f(h));
                if (m < 2 * C_Q) {
                    qkTh[(size_t)n * (2 * C_Q) + m] = h;
                    qkTl[(size_t)n * (2 * C_Q) + m] = lo;
                } else {
                    Vh[(size_t)(m - 2 * C_Q) * HW_N + n] = h;
                    Vl[(size_t)(m - 2 * C_Q) * HW_N + n] = lo;
                }
            }
}

// ---------------------------------------------------------------------------
// S = q^T k GEMM: S[m,n] = sum_k q[k,m]*k[k,n], 3-term fp16 hi/lo, K = 64.
// All of K fits in LDS at a 256x256 tile (128 KB): stage everything (16
// gl2lds/wave) -> ONE barrier -> 192 MFMA/wave uninterrupted -> exp/rowsum
// epilogue.  512 threads, 8 waves (4m x 2n), wave-tile 64x128.
// Grid (16,16) per batch = 256 blocks = 1 block/CU, write-bound regime.
// ---------------------------------------------------------------------------
__global__ __launch_bounds__(512, 2) void qkgemm(const ushort_t* __restrict__ qkTh_,
                                                 const ushort_t* __restrict__ qkTl_,
                                                 float* __restrict__ outF,
                                                 float* __restrict__ Dsum) {
    __shared__ ushort_t sAh[2][256 * 32];
    __shared__ ushort_t sAl[2][256 * 32];
    __shared__ ushort_t sBh[2][256 * 32];
    __shared__ ushort_t sBl[2][256 * 32];

    const int tid = threadIdx.x, w = tid >> 6, lane = tid & 63;
    const int quad = lane >> 4, lr = lane & 15;
    const int m0 = blockIdx.y * 256, n0 = blockIdx.x * 256;

    // staging: wave w owns panel (mat = w>>1, ks = w&1); 16 chunks of
    // 16 rows x 64B.  mat: 0=q-hi, 1=q-lo, 2=k-hi, 3=k-lo.
    const int mat = w >> 1, ks = w & 1;
    const ushort_t* src = ((mat & 1) ? qkTl_ : qkTh_) + ((mat >> 1) ? C_Q : 0);
    ushort_t* dst0 = ((mat == 0) ? sAh : (mat == 1) ? sAl
                    : (mat == 2) ? sBh : sBl)[ks];
    const int rowBase = (mat >> 1) ? n0 : m0;
    const int cr = lane >> 2, uv = lane & 3;
    const int kcol = (uv ^ ((cr >> 1) & 3)) << 3;   // pre-swizzled 16B k-unit
    const ushort_t* gk = src + (size_t)(rowBase + cr) * (2 * C_Q) + ks * 32 + kcol;

    const int wm = (w & 3) * 64, wn = (w >> 2) * 128;
    const int up = (quad ^ ((lr >> 1) & 3)) << 3;   // read-side swizzle

    // stage the ENTIRE K range, one barrier
#pragma unroll
    for (int c = 0; c < 16; c++)
        gl2lds16(gk + (size_t)(c * 16) * (2 * C_Q), dst0 + c * 512);

    float4v acc[4][8];
#pragma unroll
    for (int i = 0; i < 4; i++)
#pragma unroll
        for (int j = 0; j < 8; j++) acc[i][j] = (float4v){0.f, 0.f, 0.f, 0.f};

    __syncthreads();   // all panels resident

#pragma unroll
    for (int k2 = 0; k2 < 2; k2++) {
        short8 bh[8], bl[8];
#pragma unroll
        for (int j = 0; j < 8; j++) {
            const int row = wn + j * 16 + lr;
            bh[j] = *(const short8*)&sBh[k2][row * 32 + up];
            bl[j] = *(const short8*)&sBl[k2][row * 32 + up];
        }
#pragma unroll
        for (int i = 0; i < 4; i++) {
            const int row = wm + i * 16 + lr;
            short8 ah = *(const short8*)&sAh[k2][row * 32 + up];
            short8 al = *(const short8*)&sAl[k2][row * 32 + up];
#pragma unroll
            for (int j = 0; j < 8; j++)
                acc[i][j] = __builtin_amdgcn_mfma_f32_16x16x32_f16(ah, bh[j], acc[i][j], 0, 0, 0);
#pragma unroll
            for (int j = 0; j < 8; j++)
                acc[i][j] = __builtin_amdgcn_mfma_f32_16x16x32_f16(ah, bl[j], acc[i][j], 0, 0, 0);
#pragma unroll
            for (int j = 0; j < 8; j++)
                acc[i][j] = __builtin_amdgcn_mfma_f32_16x16x32_f16(al, bh[j], acc[i][j], 0, 0, 0);
        }
    }

    // epilogue: store S + fused per-row exp-sum partials
#pragma unroll
    for (int i = 0; i < 4; i++) {
#pragma unroll
        for (int r = 0; r < 4; r++) {
            float s = 0.f;
#pragma unroll
            for (int j = 0; j < 8; j++) {
                const int m = m0 + wm + i * 16 + quad * 4 + r;
                const int n = n0 + wn + j * 16 + lr;
                outF[(size_t)m * HW_N + n] = acc[i][j][r];
                s += __expf(acc[i][j][r]);
            }
            s += __shfl_xor(s, 1);
            s += __shfl_xor(s, 2);
            s += __shfl_xor(s, 4);
            s += __shfl_xor(s, 8);
            if (lr == 0)
                atomicAdd(&Dsum[m0 + wm + i * 16 + quad * 4 + r], s);
        }
    }
}

// ---------------------------------------------------------------------------
// feat GEMM v5 (round-9): res[m,n] = sum_k (Vh+Vl)[m,k] * P[n,k],
//   P[n,k] = alpha * f16-path( exp2(S[n,k]*log2e - log2 D[n]) )
// Round-9 change: z-slice partial planes + reduce kernel ELIMINATED.
// alpha is folded into P (PV is linear in P), and every z-slice block
// accumulates into out with native fp32 atomics (unsafeAtomicAdd ->
// global_atomic_add_f32, no CAS).  out is zeroed once up front.
// Atomic traffic = same 67 MB the plane stores cost; reduce's 75 MB
// read-back disappears.  Rest identical to v4.1 (2-iter S prefetch,
// B-frags before convert, LDS 96 KB, grid (16,2,8)).
// ---------------------------------------------------------------------------
__global__ __launch_bounds__(512, 2) void feat8(const ushort_t* __restrict__ Vh,
                                                const ushort_t* __restrict__ Vl,
                                                const float* __restrict__ S,
                                                const float* __restrict__ D,
                                                float* __restrict__ out,
                                                const float* __restrict__ alpha,
                                                int kLen) {
    __shared__ ushort_t sVh[2][256 * 32];
    __shared__ ushort_t sVl[2][256 * 32];
    __shared__ ushort_t sP [2][256 * 32];

    const int tid = threadIdx.x, w = tid >> 6, lane = tid & 63;
    const int quad = lane >> 4, lr = lane & 15;
    const int m0 = blockIdx.y * 256, n0 = blockIdx.x * 256;
    const int k0 = blockIdx.z * kLen;
    const float a = alpha[0];

    // V staging: waves 0-3 -> Vh chunks (w&3)*4..+3, waves 4-7 -> Vl ditto.
    const int crv = lane >> 2, uv = lane & 3;
    const int vcol = (uv ^ ((crv >> 1) & 3)) << 3;   // swizzled 16B unit
    const ushort_t* vbase = (w < 4) ? Vh : Vl;
    const ushort_t* gVsrc[4];
    int sOfs[4];
#pragma unroll
    for (int c = 0; c < 4; c++) {
        const int chunk = ((w & 3) * 4 + c);         // 0..15 within h or l
        gVsrc[c] = vbase + (size_t)(m0 + chunk * 16 + crv) * HW_N + vcol + k0;
        sOfs[c] = chunk * 512;
    }

    // S prefetch: thread owns rows pr+64c (c=0..3), 4-float k-unit pu.
    const int pr = tid >> 3, pu = tid & 7;
    const float* gS = S + (size_t)(n0 + pr) * HW_N + k0 + pu * 4;
    const int pdst = (((pu >> 1) ^ ((pr >> 1) & 3)) << 3) + ((pu & 1) << 2);
    float lrw[4];
#pragma unroll
    for (int c = 0; c < 4; c++) lrw[c] = -log2f(D[n0 + pr + 64 * c]);

    const int wm = (w & 3) * 64, wn = (w >> 2) * 128;

    float4 sreg[4];
    const int nIter = kLen >> 5;

    // prologue: load S(0), convert -> sP[0], prefetch S(1), stage V(0)
    {
#pragma unroll
        for (int c = 0; c < 4; c++)
            sreg[c] = *(const float4*)(gS + (size_t)(64 * c) * HW_N);
#pragma unroll
        for (int c = 0; c < 4; c++) gl2lds16(gVsrc[c], ((w < 4) ? sVh : sVl)[0] + sOfs[c]);
#pragma unroll
        for (int c = 0; c < 4; c++) {
            ushort_t h4[4];
            h4[0] = f2h(a * exp2f(fmaf(sreg[c].x, LOG2E, lrw[c])));
            h4[1] = f2h(a * exp2f(fmaf(sreg[c].y, LOG2E, lrw[c])));
            h4[2] = f2h(a * exp2f(fmaf(sreg[c].z, LOG2E, lrw[c])));
            h4[3] = f2h(a * exp2f(fmaf(sreg[c].w, LOG2E, lrw[c])));
            *(short4v*)&sP[0][(pr + 64 * c) * 32 + pdst] = *(short4v*)h4;
        }
        if (nIter > 1) {
#pragma unroll
            for (int c = 0; c < 4; c++)
                sreg[c] = *(const float4*)(gS + (size_t)(64 * c) * HW_N + 32);
        }
    }
    __syncthreads();  // V(0) + sP[0] visible

    float4v acc[4][8];
#pragma unroll
    for (int i = 0; i < 4; i++)
#pragma unroll
        for (int j = 0; j < 8; j++) acc[i][j] = (float4v){0.f, 0.f, 0.f, 0.f};

    for (int it = 0; it < nIter; ++it) {
        const int kk = it << 5;
        const int cur = it & 1, nxt = cur ^ 1;

        // issue next V tile first — flies through the whole MFMA section
        if (it + 1 < nIter) {
            ushort_t* db = ((w < 4) ? sVh : sVl)[nxt];
#pragma unroll
            for (int c = 0; c < 4; c++) gl2lds16(gVsrc[c] + kk + 32, db + sOfs[c]);
        }

        // B fragments FIRST: their ds_read latency hides under the convert
        short8 bh[8];
#pragma unroll
        for (int j = 0; j < 8; j++) {
            const int row = wn + j * 16 + lr;
            bh[j] = *(const short8*)&sP[cur][row * 32 + ((quad ^ ((lr >> 1) & 3)) << 3)];
        }

        // convert S(it+1) (in regs) -> sP[nxt]; overlaps other waves' MFMA.
        if (it + 1 < nIter) {
#pragma unroll
            for (int c = 0; c < 4; c++) {
                ushort_t h4[4];
                h4[0] = f2h(a * exp2f(fmaf(sreg[c].x, LOG2E, lrw[c])));
                h4[1] = f2h(a * exp2f(fmaf(sreg[c].y, LOG2E, lrw[c])));
                h4[2] = f2h(a * exp2f(fmaf(sreg[c].z, LOG2E, lrw[c])));
                h4[3] = f2h(a * exp2f(fmaf(sreg[c].w, LOG2E, lrw[c])));
                *(short4v*)&sP[nxt][(pr + 64 * c) * 32 + pdst] = *(short4v*)h4;
            }
            if (it + 2 < nIter) {
#pragma unroll
                for (int c = 0; c < 4; c++)
                    sreg[c] = *(const float4*)(gS + (size_t)(64 * c) * HW_N + kk + 64);
            }
        }

#pragma unroll
        for (int i = 0; i < 4; i++) {
            const int row = wm + i * 16 + lr;
            const int up = (quad ^ ((lr >> 1) & 3)) << 3;
            short8 ah = *(const short8*)&sVh[cur][row * 32 + up];
            short8 al = *(const short8*)&sVl[cur][row * 32 + up];
#pragma unroll
            for (int j = 0; j < 8; j++)
                acc[i][j] = __builtin_amdgcn_mfma_f32_16x16x32_f16(ah, bh[j], acc[i][j], 0, 0, 0);
#pragma unroll
            for (int j = 0; j < 8; j++)
                acc[i][j] = __builtin_amdgcn_mfma_f32_16x16x32_f16(al, bh[j], acc[i][j], 0, 0, 0);
        }
        __syncthreads();  // drains: vbuf[nxt] gl2lds, sP[nxt] writes; orders WAR
    }

    // epilogue: fp32 atomic accumulate into out (all z-slices; out pre-zeroed)
#pragma unroll
    for (int i = 0; i < 4; i++)
#pragma unroll
        for (int j = 0; j < 8; j++)
#pragma unroll
            for (int r = 0; r < 4; r++) {
                const int m = m0 + wm + i * 16 + quad * 4 + r;
                const int n = n0 + wn + j * 16 + lr;
                unsafeAtomicAdd(&out[(size_t)m * HW_N + n], acc[i][j][r]);
            }
}

// ---------------------------------------------------------------------------

extern "C" void kernel_launch(void* const* d_in, const int* in_sizes, int n_in,
                              void* d_out, int out_size, void* d_ws, size_t ws_size,
                              hipStream_t stream) {
    const float* x     = (const float*)d_in[0];
    const float* Wq    = (const float*)d_in[1];
    const float* bq    = (const float*)d_in[2];
    const float* Wk    = (const float*)d_in[3];
    const float* bk    = (const float*)d_in[4];
    const float* Wv    = (const float*)d_in[5];
    const float* bv    = (const float*)d_in[6];
    const float* alpha = (const float*)d_in[7];
    float* out = (float*)d_out;

    const size_t planeQK = (size_t)HW_N * 2 * C_Q;   // qkT elems / batch
    const size_t planeV  = (size_t)C_IN * HW_N;      // V (and out) elems / batch
    const size_t planeXT = (size_t)HW_N * C_IN;      // xT elems / batch
    const size_t planeW  = (size_t)M_YP * C_IN;      // padded W
    const size_t planeS  = (size_t)HW_N * HW_N;

    // --- fused (4-batch) layout -------------------------------------------
    //   D4          : 4 x 4096 fp32
    //   qkTh4/qkTl4 : 4 x planeQK fp16 each        (8.4 MB)
    //   Vh4/Vl4     : 4 x planeV fp16 each         (33.6 MB)
    //   Wh/Wl       : planeW fp16 each             (1.6 MB, padded)
    //   scores      : planeS fp32                  (67.1 MB)
    //     overlay (dead after ygemm): xTh4/xTl4    (33.6 MB <= 67.1 OK)
    // total ~112 MB (partial planes eliminated in round 9)
    const size_t fusedBytes =
        (size_t)NB * HW_N * 4 + 2 * (size_t)NB * planeQK * 2 +
        2 * (size_t)NB * planeV * 2 + 2 * planeW * 2 + planeS * 4;
    const bool fused = (ws_size >= fusedBytes);

    const int nOut4 = (int)((size_t)NB * planeV / 4);

    if (fused) {
        float* D4      = (float*)d_ws;
        ushort_t* qkTh4 = (ushort_t*)(D4 + (size_t)NB * HW_N);
        ushort_t* qkTl4 = qkTh4 + (size_t)NB * planeQK;
        ushort_t* Vh4   = qkTl4 + (size_t)NB * planeQK;
        ushort_t* Vl4   = Vh4 + (size_t)NB * planeV;
        ushort_t* Wh    = Vl4 + (size_t)NB * planeV;
        ushort_t* Wl    = Wh + planeW;
        float* scores   = (float*)(Wl + planeW);
        ushort_t* xTh4  = (ushort_t*)scores;           // overlay
        ushort_t* xTl4  = xTh4 + (size_t)NB * planeXT;

        split_w<<<dim3(M_YP * C_IN / 4 / 256), dim3(256), 0, stream>>>(Wq, Wk, Wv, Wh, Wl);
        zero_out<<<dim3((nOut4 + 255) / 256), dim3(256), 0, stream>>>(
            (float4*)out, nOut4);

        // all 4 batches in one dispatch each
        split_x<<<dim3(HW_N / 64, C_IN / 64, NB), dim3(256), 0, stream>>>(
            x, xTh4, xTl4, D4);
        ygemm<<<dim3(HW_N / 256, M_YP / 256, NB), dim3(512), 0, stream>>>(
            Wh, Wl, xTh4, xTl4, bq, bk, bv, qkTh4, qkTl4, Vh4, Vl4);
        // (xT region dead from here on; scores may overwrite it)

        for (int b = 0; b < NB; b++) {
            float* outb = out + (size_t)b * planeV;
            qkgemm<<<dim3(HW_N / 256, HW_N / 256), dim3(512), 0, stream>>>(
                qkTh4 + (size_t)b * planeQK, qkTl4 + (size_t)b * planeQK,
                scores, D4 + (size_t)b * HW_N);
            feat8<<<dim3(HW_N / 256, C_IN / 256, 8), dim3(512), 0, stream>>>(
                Vh4 + (size_t)b * planeV, Vl4 + (size_t)b * planeV,
                scores, D4 + (size_t)b * HW_N, outb, alpha, HW_N / 8);
        }
        return;
    }

    // --- fallback: per-batch layout + loop -------------------------------
    float* D = (float*)d_ws;
    ushort_t* qkTh = (ushort_t*)(D + HW_N);
    ushort_t* qkTl = qkTh + planeQK;
    ushort_t* Vh   = qkTl + planeQK;
    ushort_t* Vl   = Vh + planeV;
    ushort_t* Wh   = Vl + planeV;
    ushort_t* Wl   = Wh + planeW;
    float* scores  = (float*)(Wl + planeW);
    ushort_t* xTh  = (ushort_t*)scores;
    ushort_t* xTl  = xTh + planeXT;

    split_w<<<dim3(M_YP * C_IN / 4 / 256), dim3(256), 0, stream>>>(Wq, Wk, Wv, Wh, Wl);
    zero_out<<<dim3((nOut4 + 255) / 256), dim3(256), 0, stream>>>(
        (float4*)out, nOut4);

    for (int b = 0; b < NB; b++) {
        const float* xb = x + (size_t)b * planeV;
        float* outb = out + (size_t)b * planeV;

        split_x<<<dim3(HW_N / 64, C_IN / 64, 1), dim3(256), 0, stream>>>(
            xb, xTh, xTl, D);
        ygemm<<<dim3(HW_N / 256, M_YP / 256, 1), dim3(512), 0, stream>>>(
            Wh, Wl, xTh, xTl, bq, bk, bv, qkTh, qkTl, Vh, Vl);
        qkgemm<<<dim3(HW_N / 256, HW_N / 256), dim3(512), 0, stream>>>(
            qkTh, qkTl, scores, D);
        feat8<<<dim3(HW_N / 256, C_IN / 256, 8), dim3(512), 0, stream>>>(
            Vh, Vl, scores, D, outb, alpha, HW_N / 8);
    }
}

// Round 10
// 574.003 us; speedup vs baseline: 1.0281x; 1.0281x over previous
//
#include <hip/hip_runtime.h>
#include <hip/hip_fp16.h>

// Problem constants (fixed by setup_inputs)
#define HW_N 4096   // 64*64 spatial positions
#define C_IN 512    // channels
#define C_Q  64     // query/key channels
#define NB   4      // batch
#define M_Y  640    // Cq + Cq + C stacked output rows
#define M_YP 768    // M_Y padded (multiple of 192 and 256; rows 640-767 zero)
#define LOG2E 1.4426950408889634f

typedef __attribute__((ext_vector_type(8))) short short8;
typedef __attribute__((ext_vector_type(4))) short short4v;
typedef __attribute__((ext_vector_type(4))) float float4v;
typedef unsigned short ushort_t;

__device__ __forceinline__ ushort_t f2h(float x) {
    return __half_as_ushort(__float2half(x));  // RNE
}
__device__ __forceinline__ float h2f(ushort_t h) {
    return __half2float(__ushort_as_half(h));
}
__device__ __forceinline__ void gl2lds16(const ushort_t* g, ushort_t* l) {
    __builtin_amdgcn_global_load_lds(
        (const __attribute__((address_space(1))) unsigned int*)g,
        (__attribute__((address_space(3))) unsigned int*)l, 16, 0, 0);
}

// ---------------------------------------------------------------------------
// split stacked W = [Wq;Wk;Wv;0-pad] (768x512 fp32) -> fp16 hi/lo
// ---------------------------------------------------------------------------
__global__ __launch_bounds__(256) void split_w(const float* __restrict__ Wq,
                                               const float* __restrict__ Wk,
                                               const float* __restrict__ Wv,
                                               ushort_t* __restrict__ Wh,
                                               ushort_t* __restrict__ Wl) {
    int idx = (blockIdx.x * 256 + threadIdx.x) * 4;
#pragma unroll
    for (int e = 0; e < 4; e++) {
        int i = idx + e;
        int m = i >> 9, k = i & 511;
        float v = (m < C_Q) ? Wq[m * C_IN + k]
                 : (m < 2 * C_Q) ? Wk[(m - C_Q) * C_IN + k]
                 : (m < M_Y) ? Wv[(size_t)(m - 2 * C_Q) * C_IN + k]
                 : 0.f;                              // zero pad rows 640-767
        ushort_t h = f2h(v);
        Wh[i] = h;
        Wl[i] = f2h(v - h2f(h));
    }
}

// zero the whole output tensor (out accumulates via fp32 atomics in feat8)
__global__ __launch_bounds__(256) void zero_out(float4* __restrict__ p, int n4) {
    int i = blockIdx.x * 256 + threadIdx.x;
    if (i < n4) p[i] = (float4){0.f, 0.f, 0.f, 0.f};
}

// ---------------------------------------------------------------------------
// transpose + split: x [512][4096] fp32 -> xT hi/lo [4096][512] fp16
// blockIdx.z selects the batch.  Also zeroes this batch's D[4096].
// ---------------------------------------------------------------------------
__global__ __launch_bounds__(256) void split_x(const float* __restrict__ x,
                                               ushort_t* __restrict__ xTh,
                                               ushort_t* __restrict__ xTl,
                                               float* __restrict__ D) {
    const size_t bz = blockIdx.z;
    x   += bz * ((size_t)C_IN * HW_N);
    xTh += bz * ((size_t)HW_N * C_IN);
    xTl += bz * ((size_t)HW_N * C_IN);
    D   += bz * HW_N;

    if (blockIdx.y == 0 && blockIdx.x < 16) D[blockIdx.x * 256 + threadIdx.x] = 0.f;

    __shared__ float tile[64][65];
    const int n0 = blockIdx.x * 64, k0 = blockIdx.y * 64;
    const int t = threadIdx.x;
#pragma unroll
    for (int it = 0; it < 4; it++) {
        int e = t + it * 256;
        int r = e >> 4, c4 = (e & 15) << 2;
        float4 v = *(const float4*)(x + (size_t)(k0 + r) * HW_N + n0 + c4);
        tile[r][c4 + 0] = v.x; tile[r][c4 + 1] = v.y;
        tile[r][c4 + 2] = v.z; tile[r][c4 + 3] = v.w;
    }
    __syncthreads();
    const int rr = t >> 2, kq = (t & 3) << 4;
    ushort_t h[16], l[16];
#pragma unroll
    for (int j = 0; j < 16; j++) {
        float v = tile[kq + j][rr];
        h[j] = f2h(v);
        l[j] = f2h(v - h2f(h[j]));
    }
    size_t o = (size_t)(n0 + rr) * C_IN + k0 + kq;
    *(uint4*)(xTh + o) = *(uint4*)h;
    *(uint4*)(xTh + o + 8) = *(uint4*)(h + 8);
    *(uint4*)(xTl + o) = *(uint4*)l;
    *(uint4*)(xTl + o + 8) = *(uint4*)(l + 8);
}

// ---------------------------------------------------------------------------
// Y = W*x + b GEMM v3 (round-10): 192m x 256n tile, 512 threads = 8 waves
// (4m x 2n), wave-tile 48x128 (acc[3][8]).  Round-9 PMC: the 256m tile gave
// grid (16,3,NB) = 192 blocks at 1 block/CU -> 64 CUs idle.  192-row M tiles
// (M_YP = 768 = 4x192) give grid (16,4,NB) = 256 blocks = every CU busy.
// LDS 112 KB (A: 2x192x32 h+l = 48K, B: 2x256x32 h+l = 64K), 1 block/CU.
// Staging: A-side waves 6 chunks each (12 per matrix), B-side 8.
// Same single-barrier double-buffered pipeline + swizzle as before
// (swizzle keyed on row mod 16; 48 is a multiple of 16 so reads align).
// ---------------------------------------------------------------------------
__global__ __launch_bounds__(512, 2) void ygemm(
    const ushort_t* __restrict__ Ah, const ushort_t* __restrict__ Al,
    const ushort_t* __restrict__ Bh, const ushort_t* __restrict__ Bl,
    const float* __restrict__ bq, const float* __restrict__ bk,
    const float* __restrict__ bv,
    ushort_t* __restrict__ qkTh, ushort_t* __restrict__ qkTl,
    ushort_t* __restrict__ Vh, ushort_t* __restrict__ Vl) {
    const size_t bz = blockIdx.z;
    Bh   += bz * ((size_t)HW_N * C_IN);
    Bl   += bz * ((size_t)HW_N * C_IN);
    qkTh += bz * ((size_t)HW_N * 2 * C_Q);
    qkTl += bz * ((size_t)HW_N * 2 * C_Q);
    Vh   += bz * ((size_t)C_IN * HW_N);
    Vl   += bz * ((size_t)C_IN * HW_N);

    __shared__ ushort_t sAh[2][192 * 32];
    __shared__ ushort_t sAl[2][192 * 32];
    __shared__ ushort_t sBh[2][256 * 32];
    __shared__ ushort_t sBl[2][256 * 32];

    const int tid = threadIdx.x, w = tid >> 6, lane = tid & 63;
    const int quad = lane >> 4, lr = lane & 15;
    const int m0 = blockIdx.y * 192, n0 = blockIdx.x * 256;

    // staging partition: waves 0-1 -> Ah (6 chunks each), 2-3 -> Al,
    // 4-5 -> Bh (8 each), 6-7 -> Bl.  chunk = 16 rows x 32 k x 2B = 1 KB.
    const int cr = lane >> 2, uv = lane & 3;
    const int kcol = (uv ^ ((cr >> 1) & 3)) << 3;   // pre-swizzled 16B k-unit
    const ushort_t* src;
    ushort_t* dst0;
    int rowBase, chunk0, bufStride;
    if (w < 4) {
        src = (w < 2) ? Ah : Al;
        dst0 = (w < 2) ? sAh[0] : sAl[0];
        rowBase = m0; chunk0 = (w & 1) * 6; bufStride = 192 * 32;
    } else {
        src = (w < 6) ? Bh : Bl;
        dst0 = (w < 6) ? sBh[0] : sBl[0];
        rowBase = n0; chunk0 = (w & 1) * 8; bufStride = 256 * 32;
    }
    const ushort_t* gk = src + (size_t)(rowBase + chunk0 * 16 + cr) * C_IN + kcol;
    ushort_t* dstw = dst0 + chunk0 * 512;

    const int wm = (w & 3) * 48, wn = (w >> 2) * 128;
    const int up = (quad ^ ((lr >> 1) & 3)) << 3;   // read-side swizzle

    float4v acc[3][8];
#pragma unroll
    for (int i = 0; i < 3; i++)
#pragma unroll
        for (int j = 0; j < 8; j++) acc[i][j] = (float4v){0.f, 0.f, 0.f, 0.f};

    // prologue: stage k-step 0 into buf 0
    if (w < 4) {
#pragma unroll
        for (int c = 0; c < 6; c++)
            gl2lds16(gk + (size_t)(c * 16) * C_IN, dstw + c * 512);
    } else {
#pragma unroll
        for (int c = 0; c < 8; c++)
            gl2lds16(gk + (size_t)(c * 16) * C_IN, dstw + c * 512);
    }
    __syncthreads();

    const int NSTEP = C_IN / 32;    // 16
    for (int it = 0; it < NSTEP; ++it) {
        const int cur = it & 1, nxt = cur ^ 1;

        // issue next k-step's loads first — they fly over the MFMA section
        if (it + 1 < NSTEP) {
            ushort_t* db = dstw + nxt * bufStride;
            const ushort_t* gn = gk + (it + 1) * 32;
            if (w < 4) {
#pragma unroll
                for (int c = 0; c < 6; c++)
                    gl2lds16(gn + (size_t)(c * 16) * C_IN, db + c * 512);
            } else {
#pragma unroll
                for (int c = 0; c < 8; c++)
                    gl2lds16(gn + (size_t)(c * 16) * C_IN, db + c * 512);
            }
        }

        // B fragments upfront (reused by all 3 i); A per-i
        short8 bh[8], bl[8];
#pragma unroll
        for (int j = 0; j < 8; j++) {
            const int row = wn + j * 16 + lr;
            bh[j] = *(const short8*)&sBh[cur][row * 32 + up];
            bl[j] = *(const short8*)&sBl[cur][row * 32 + up];
        }
#pragma unroll
        for (int i = 0; i < 3; i++) {
            const int row = wm + i * 16 + lr;
            short8 ah = *(const short8*)&sAh[cur][row * 32 + up];
            short8 al = *(const short8*)&sAl[cur][row * 32 + up];
#pragma unroll
            for (int j = 0; j < 8; j++)
                acc[i][j] = __builtin_amdgcn_mfma_f32_16x16x32_f16(ah, bh[j], acc[i][j], 0, 0, 0);
#pragma unroll
            for (int j = 0; j < 8; j++)
                acc[i][j] = __builtin_amdgcn_mfma_f32_16x16x32_f16(ah, bl[j], acc[i][j], 0, 0, 0);
#pragma unroll
            for (int j = 0; j < 8; j++)
                acc[i][j] = __builtin_amdgcn_mfma_f32_16x16x32_f16(al, bh[j], acc[i][j], 0, 0, 0);
        }
        __syncthreads();  // drains nxt's gl2lds (flew over MFMA); orders WAR
    }

    // epilogue: +bias, fp16 hi/lo split; m<128 -> qkT (transposed), else V;
    // padded rows (m >= 640) skipped.
#pragma unroll
    for (int i = 0; i < 3; i++)
#pragma unroll
        for (int j = 0; j < 8; j++)
#pragma unroll
            for (int r = 0; r < 4; r++) {
                const int m = m0 + wm + i * 16 + quad * 4 + r;
                if (m >= M_Y) continue;
                const int n = n0 + wn + j * 16 + lr;
                float bi = (m < C_Q) ? bq[m]
                          : (m < 2 * C_Q) ? bk[m - C_Q] : bv[m - 2 * C_Q];
                float v = acc[i][j][r] + bi;
                ushort_t h = f2h(v);
                ushort_t lo = f2h(v - h2f(h));
                if (m < 2 * C_Q) {
                    qkTh[(size_t)n * (2 * C_Q) + m] = h;
                    qkTl[(size_t)n * (2 * C_Q) + m] = lo;
                } else {
                    Vh[(size_t)(m - 2 * C_Q) * HW_N + n] = h;
                    Vl[(size_t)(m - 2 * C_Q) * HW_N + n] = lo;
                }
            }
}

// ---------------------------------------------------------------------------
// S = q^T k GEMM: S[m,n] = sum_k q[k,m]*k[k,n], 3-term fp16 hi/lo, K = 64.
// All of K fits in LDS at a 256x256 tile (128 KB): stage everything (16
// gl2lds/wave) -> ONE barrier -> 192 MFMA/wave uninterrupted -> exp/rowsum
// epilogue.  512 threads, 8 waves (4m x 2n), wave-tile 64x128.
// Grid (16,16) per batch = 256 blocks = 1 block/CU, write-bound regime.
// ---------------------------------------------------------------------------
__global__ __launch_bounds__(512, 2) void qkgemm(const ushort_t* __restrict__ qkTh_,
                                                 const ushort_t* __restrict__ qkTl_,
                                                 float* __restrict__ outF,
                                                 float* __restrict__ Dsum) {
    __shared__ ushort_t sAh[2][256 * 32];
    __shared__ ushort_t sAl[2][256 * 32];
    __shared__ ushort_t sBh[2][256 * 32];
    __shared__ ushort_t sBl[2][256 * 32];

    const int tid = threadIdx.x, w = tid >> 6, lane = tid & 63;
    const int quad = lane >> 4, lr = lane & 15;
    const int m0 = blockIdx.y * 256, n0 = blockIdx.x * 256;

    // staging: wave w owns panel (mat = w>>1, ks = w&1); 16 chunks of
    // 16 rows x 64B.  mat: 0=q-hi, 1=q-lo, 2=k-hi, 3=k-lo.
    const int mat = w >> 1, ks = w & 1;
    const ushort_t* src = ((mat & 1) ? qkTl_ : qkTh_) + ((mat >> 1) ? C_Q : 0);
    ushort_t* dst0 = ((mat == 0) ? sAh : (mat == 1) ? sAl
                    : (mat == 2) ? sBh : sBl)[ks];
    const int rowBase = (mat >> 1) ? n0 : m0;
    const int cr = lane >> 2, uv = lane & 3;
    const int kcol = (uv ^ ((cr >> 1) & 3)) << 3;   // pre-swizzled 16B k-unit
    const ushort_t* gk = src + (size_t)(rowBase + cr) * (2 * C_Q) + ks * 32 + kcol;

    const int wm = (w & 3) * 64, wn = (w >> 2) * 128;
    const int up = (quad ^ ((lr >> 1) & 3)) << 3;   // read-side swizzle

    // stage the ENTIRE K range, one barrier
#pragma unroll
    for (int c = 0; c < 16; c++)
        gl2lds16(gk + (size_t)(c * 16) * (2 * C_Q), dst0 + c * 512);

    float4v acc[4][8];
#pragma unroll
    for (int i = 0; i < 4; i++)
#pragma unroll
        for (int j = 0; j < 8; j++) acc[i][j] = (float4v){0.f, 0.f, 0.f, 0.f};

    __syncthreads();   // all panels resident

#pragma unroll
    for (int k2 = 0; k2 < 2; k2++) {
        short8 bh[8], bl[8];
#pragma unroll
        for (int j = 0; j < 8; j++) {
            const int row = wn + j * 16 + lr;
            bh[j] = *(const short8*)&sBh[k2][row * 32 + up];
            bl[j] = *(const short8*)&sBl[k2][row * 32 + up];
        }
#pragma unroll
        for (int i = 0; i < 4; i++) {
            const int row = wm + i * 16 + lr;
            short8 ah = *(const short8*)&sAh[k2][row * 32 + up];
            short8 al = *(const short8*)&sAl[k2][row * 32 + up];
#pragma unroll
            for (int j = 0; j < 8; j++)
                acc[i][j] = __builtin_amdgcn_mfma_f32_16x16x32_f16(ah, bh[j], acc[i][j], 0, 0, 0);
#pragma unroll
            for (int j = 0; j < 8; j++)
                acc[i][j] = __builtin_amdgcn_mfma_f32_16x16x32_f16(ah, bl[j], acc[i][j], 0, 0, 0);
#pragma unroll
            for (int j = 0; j < 8; j++)
                acc[i][j] = __builtin_amdgcn_mfma_f32_16x16x32_f16(al, bh[j], acc[i][j], 0, 0, 0);
        }
    }

    // epilogue: store S + fused per-row exp-sum partials
#pragma unroll
    for (int i = 0; i < 4; i++) {
#pragma unroll
        for (int r = 0; r < 4; r++) {
            float s = 0.f;
#pragma unroll
            for (int j = 0; j < 8; j++) {
                const int m = m0 + wm + i * 16 + quad * 4 + r;
                const int n = n0 + wn + j * 16 + lr;
                outF[(size_t)m * HW_N + n] = acc[i][j][r];
                s += __expf(acc[i][j][r]);
            }
            s += __shfl_xor(s, 1);
            s += __shfl_xor(s, 2);
            s += __shfl_xor(s, 4);
            s += __shfl_xor(s, 8);
            if (lr == 0)
                atomicAdd(&Dsum[m0 + wm + i * 16 + quad * 4 + r], s);
        }
    }
}

// ---------------------------------------------------------------------------
// feat GEMM v5: res[m,n] = sum_k (Vh+Vl)[m,k] * P[n,k],
//   P[n,k] = alpha * f16-path( exp2(S[n,k]*log2e - log2 D[n]) )
// alpha folded into P (PV linear in P); every z-slice block accumulates
// into out with native fp32 atomics (unsafeAtomicAdd).  out pre-zeroed.
// 2-iter S prefetch, B-frags before convert, LDS 96 KB, grid (16,2,8).
// ---------------------------------------------------------------------------
__global__ __launch_bounds__(512, 2) void feat8(const ushort_t* __restrict__ Vh,
                                                const ushort_t* __restrict__ Vl,
                                                const float* __restrict__ S,
                                                const float* __restrict__ D,
                                                float* __restrict__ out,
                                                const float* __restrict__ alpha,
                                                int kLen) {
    __shared__ ushort_t sVh[2][256 * 32];
    __shared__ ushort_t sVl[2][256 * 32];
    __shared__ ushort_t sP [2][256 * 32];

    const int tid = threadIdx.x, w = tid >> 6, lane = tid & 63;
    const int quad = lane >> 4, lr = lane & 15;
    const int m0 = blockIdx.y * 256, n0 = blockIdx.x * 256;
    const int k0 = blockIdx.z * kLen;
    const float a = alpha[0];

    // V staging: waves 0-3 -> Vh chunks (w&3)*4..+3, waves 4-7 -> Vl ditto.
    const int crv = lane >> 2, uv = lane & 3;
    const int vcol = (uv ^ ((crv >> 1) & 3)) << 3;   // swizzled 16B unit
    const ushort_t* vbase = (w < 4) ? Vh : Vl;
    const ushort_t* gVsrc[4];
    int sOfs[4];
#pragma unroll
    for (int c = 0; c < 4; c++) {
        const int chunk = ((w & 3) * 4 + c);         // 0..15 within h or l
        gVsrc[c] = vbase + (size_t)(m0 + chunk * 16 + crv) * HW_N + vcol + k0;
        sOfs[c] = chunk * 512;
    }

    // S prefetch: thread owns rows pr+64c (c=0..3), 4-float k-unit pu.
    const int pr = tid >> 3, pu = tid & 7;
    const float* gS = S + (size_t)(n0 + pr) * HW_N + k0 + pu * 4;
    const int pdst = (((pu >> 1) ^ ((pr >> 1) & 3)) << 3) + ((pu & 1) << 2);
    float lrw[4];
#pragma unroll
    for (int c = 0; c < 4; c++) lrw[c] = -log2f(D[n0 + pr + 64 * c]);

    const int wm = (w & 3) * 64, wn = (w >> 2) * 128;

    float4 sreg[4];
    const int nIter = kLen >> 5;

    // prologue: load S(0), convert -> sP[0], prefetch S(1), stage V(0)
    {
#pragma unroll
        for (int c = 0; c < 4; c++)
            sreg[c] = *(const float4*)(gS + (size_t)(64 * c) * HW_N);
#pragma unroll
        for (int c = 0; c < 4; c++) gl2lds16(gVsrc[c], ((w < 4) ? sVh : sVl)[0] + sOfs[c]);
#pragma unroll
        for (int c = 0; c < 4; c++) {
            ushort_t h4[4];
            h4[0] = f2h(a * exp2f(fmaf(sreg[c].x, LOG2E, lrw[c])));
            h4[1] = f2h(a * exp2f(fmaf(sreg[c].y, LOG2E, lrw[c])));
            h4[2] = f2h(a * exp2f(fmaf(sreg[c].z, LOG2E, lrw[c])));
            h4[3] = f2h(a * exp2f(fmaf(sreg[c].w, LOG2E, lrw[c])));
            *(short4v*)&sP[0][(pr + 64 * c) * 32 + pdst] = *(short4v*)h4;
        }
        if (nIter > 1) {
#pragma unroll
            for (int c = 0; c < 4; c++)
                sreg[c] = *(const float4*)(gS + (size_t)(64 * c) * HW_N + 32);
        }
    }
    __syncthreads();  // V(0) + sP[0] visible

    float4v acc[4][8];
#pragma unroll
    for (int i = 0; i < 4; i++)
#pragma unroll
        for (int j = 0; j < 8; j++) acc[i][j] = (float4v){0.f, 0.f, 0.f, 0.f};

    for (int it = 0; it < nIter; ++it) {
        const int kk = it << 5;
        const int cur = it & 1, nxt = cur ^ 1;

        // issue next V tile first — flies through the whole MFMA section
        if (it + 1 < nIter) {
            ushort_t* db = ((w < 4) ? sVh : sVl)[nxt];
#pragma unroll
            for (int c = 0; c < 4; c++) gl2lds16(gVsrc[c] + kk + 32, db + sOfs[c]);
        }

        // B fragments FIRST: their ds_read latency hides under the convert
        short8 bh[8];
#pragma unroll
        for (int j = 0; j < 8; j++) {
            const int row = wn + j * 16 + lr;
            bh[j] = *(const short8*)&sP[cur][row * 32 + ((quad ^ ((lr >> 1) & 3)) << 3)];
        }

        // convert S(it+1) (in regs) -> sP[nxt]; overlaps other waves' MFMA.
        if (it + 1 < nIter) {
#pragma unroll
            for (int c = 0; c < 4; c++) {
                ushort_t h4[4];
                h4[0] = f2h(a * exp2f(fmaf(sreg[c].x, LOG2E, lrw[c])));
                h4[1] = f2h(a * exp2f(fmaf(sreg[c].y, LOG2E, lrw[c])));
                h4[2] = f2h(a * exp2f(fmaf(sreg[c].z, LOG2E, lrw[c])));
                h4[3] = f2h(a * exp2f(fmaf(sreg[c].w, LOG2E, lrw[c])));
                *(short4v*)&sP[nxt][(pr + 64 * c) * 32 + pdst] = *(short4v*)h4;
            }
            if (it + 2 < nIter) {
#pragma unroll
                for (int c = 0; c < 4; c++)
                    sreg[c] = *(const float4*)(gS + (size_t)(64 * c) * HW_N + kk + 64);
            }
        }

#pragma unroll
        for (int i = 0; i < 4; i++) {
            const int row = wm + i * 16 + lr;
            const int up = (quad ^ ((lr >> 1) & 3)) << 3;
            short8 ah = *(const short8*)&sVh[cur][row * 32 + up];
            short8 al = *(const short8*)&sVl[cur][row * 32 + up];
#pragma unroll
            for (int j = 0; j < 8; j++)
                acc[i][j] = __builtin_amdgcn_mfma_f32_16x16x32_f16(ah, bh[j], acc[i][j], 0, 0, 0);
#pragma unroll
            for (int j = 0; j < 8; j++)
                acc[i][j] = __builtin_amdgcn_mfma_f32_16x16x32_f16(al, bh[j], acc[i][j], 0, 0, 0);
        }
        __syncthreads();  // drains: vbuf[nxt] gl2lds, sP[nxt] writes; orders WAR
    }

    // epilogue: fp32 atomic accumulate into out (all z-slices; out pre-zeroed)
#pragma unroll
    for (int i = 0; i < 4; i++)
#pragma unroll
        for (int j = 0; j < 8; j++)
#pragma unroll
            for (int r = 0; r < 4; r++) {
                const int m = m0 + wm + i * 16 + quad * 4 + r;
                const int n = n0 + wn + j * 16 + lr;
                unsafeAtomicAdd(&out[(size_t)m * HW_N + n], acc[i][j][r]);
            }
}

// ---------------------------------------------------------------------------

extern "C" void kernel_launch(void* const* d_in, const int* in_sizes, int n_in,
                              void* d_out, int out_size, void* d_ws, size_t ws_size,
                              hipStream_t stream) {
    const float* x     = (const float*)d_in[0];
    const float* Wq    = (const float*)d_in[1];
    const float* bq    = (const float*)d_in[2];
    const float* Wk    = (const float*)d_in[3];
    const float* bk    = (const float*)d_in[4];
    const float* Wv    = (const float*)d_in[5];
    const float* bv    = (const float*)d_in[6];
    const float* alpha = (const float*)d_in[7];
    float* out = (float*)d_out;

    const size_t planeQK = (size_t)HW_N * 2 * C_Q;   // qkT elems / batch
    const size_t planeV  = (size_t)C_IN * HW_N;      // V (and out) elems / batch
    const size_t planeXT = (size_t)HW_N * C_IN;      // xT elems / batch
    const size_t planeW  = (size_t)M_YP * C_IN;      // padded W
    const size_t planeS  = (size_t)HW_N * HW_N;

    // --- fused (4-batch) layout -------------------------------------------
    //   D4          : 4 x 4096 fp32
    //   qkTh4/qkTl4 : 4 x planeQK fp16 each        (8.4 MB)
    //   Vh4/Vl4     : 4 x planeV fp16 each         (33.6 MB)
    //   Wh/Wl       : planeW fp16 each             (1.6 MB, padded)
    //   scores      : planeS fp32                  (67.1 MB)
    //     overlay (dead after ygemm): xTh4/xTl4    (33.6 MB <= 67.1 OK)
    // total ~112 MB
    const size_t fusedBytes =
        (size_t)NB * HW_N * 4 + 2 * (size_t)NB * planeQK * 2 +
        2 * (size_t)NB * planeV * 2 + 2 * planeW * 2 + planeS * 4;
    const bool fused = (ws_size >= fusedBytes);

    const int nOut4 = (int)((size_t)NB * planeV / 4);

    if (fused) {
        float* D4      = (float*)d_ws;
        ushort_t* qkTh4 = (ushort_t*)(D4 + (size_t)NB * HW_N);
        ushort_t* qkTl4 = qkTh4 + (size_t)NB * planeQK;
        ushort_t* Vh4   = qkTl4 + (size_t)NB * planeQK;
        ushort_t* Vl4   = Vh4 + (size_t)NB * planeV;
        ushort_t* Wh    = Vl4 + (size_t)NB * planeV;
        ushort_t* Wl    = Wh + planeW;
        float* scores   = (float*)(Wl + planeW);
        ushort_t* xTh4  = (ushort_t*)scores;           // overlay
        ushort_t* xTl4  = xTh4 + (size_t)NB * planeXT;

        split_w<<<dim3(M_YP * C_IN / 4 / 256), dim3(256), 0, stream>>>(Wq, Wk, Wv, Wh, Wl);
        zero_out<<<dim3((nOut4 + 255) / 256), dim3(256), 0, stream>>>(
            (float4*)out, nOut4);

        // all 4 batches in one dispatch each
        split_x<<<dim3(HW_N / 64, C_IN / 64, NB), dim3(256), 0, stream>>>(
            x, xTh4, xTl4, D4);
        ygemm<<<dim3(HW_N / 256, M_YP / 192, NB), dim3(512), 0, stream>>>(
            Wh, Wl, xTh4, xTl4, bq, bk, bv, qkTh4, qkTl4, Vh4, Vl4);
        // (xT region dead from here on; scores may overwrite it)

        for (int b = 0; b < NB; b++) {
            float* outb = out + (size_t)b * planeV;
            qkgemm<<<dim3(HW_N / 256, HW_N / 256), dim3(512), 0, stream>>>(
                qkTh4 + (size_t)b * planeQK, qkTl4 + (size_t)b * planeQK,
                scores, D4 + (size_t)b * HW_N);
            feat8<<<dim3(HW_N / 256, C_IN / 256, 8), dim3(512), 0, stream>>>(
                Vh4 + (size_t)b * planeV, Vl4 + (size_t)b * planeV,
                scores, D4 + (size_t)b * HW_N, outb, alpha, HW_N / 8);
        }
        return;
    }

    // --- fallback: per-batch layout + loop -------------------------------
    float* D = (float*)d_ws;
    ushort_t* qkTh = (ushort_t*)(D + HW_N);
    ushort_t* qkTl = qkTh + planeQK;
    ushort_t* Vh   = qkTl + planeQK;
    ushort_t* Vl   = Vh + planeV;
    ushort_t* Wh   = Vl + planeV;
    ushort_t* Wl   = Wh + planeW;
    float* scores  = (float*)(Wl + planeW);
    ushort_t* xTh  = (ushort_t*)scores;
    ushort_t* xTl  = xTh + planeXT;

    split_w<<<dim3(M_YP * C_IN / 4 / 256), dim3(256), 0, stream>>>(Wq, Wk, Wv, Wh, Wl);
    zero_out<<<dim3((nOut4 + 255) / 256), dim3(256), 0, stream>>>(
        (float4*)out, nOut4);

    for (int b = 0; b < NB; b++) {
        const float* xb = x + (size_t)b * planeV;
        float* outb = out + (size_t)b * planeV;

        split_x<<<dim3(HW_N / 64, C_IN / 64, 1), dim3(256), 0, stream>>>(
            xb, xTh, xTl, D);
        ygemm<<<dim3(HW_N / 256, M_YP / 192, 1), dim3(512), 0, stream>>>(
            Wh, Wl, xTh, xTl, bq, bk, bv, qkTh, qkTl, Vh, Vl);
        qkgemm<<<dim3(HW_N / 256, HW_N / 256), dim3(512), 0, stream>>>(
            qkTh, qkTl, scores, D);
        feat8<<<dim3(HW_N / 256, C_IN / 256, 8), dim3(512), 0, stream>>>(
            Vh, Vl, scores, D, outb, alpha, HW_N / 8);
    }
}

// Round 11
// 450.004 us; speedup vs baseline: 1.3114x; 1.2756x over previous
//
#include <hip/hip_runtime.h>
#include <hip/hip_fp16.h>

// Problem constants (fixed by setup_inputs)
#define HW_N 4096   // 64*64 spatial positions
#define C_IN 512    // channels
#define C_Q  64     // query/key channels
#define NB   4      // batch
#define M_Y  640    // Cq + Cq + C stacked output rows
#define M_YP 768    // M_Y padded (multiple of 192 and 256; rows 640-767 zero)
#define LOG2E 1.4426950408889634f

typedef __attribute__((ext_vector_type(8))) short short8;
typedef __attribute__((ext_vector_type(4))) short short4v;
typedef __attribute__((ext_vector_type(4))) float float4v;
typedef unsigned short ushort_t;

__device__ __forceinline__ ushort_t f2h(float x) {
    return __half_as_ushort(__float2half(x));  // RNE
}
__device__ __forceinline__ float h2f(ushort_t h) {
    return __half2float(__ushort_as_half(h));
}
__device__ __forceinline__ void gl2lds16(const ushort_t* g, ushort_t* l) {
    __builtin_amdgcn_global_load_lds(
        (const __attribute__((address_space(1))) unsigned int*)g,
        (__attribute__((address_space(3))) unsigned int*)l, 16, 0, 0);
}

// ---------------------------------------------------------------------------
// split stacked W = [Wq;Wk;Wv;0-pad] (768x512 fp32) -> fp16 hi/lo
// ---------------------------------------------------------------------------
__global__ __launch_bounds__(256) void split_w(const float* __restrict__ Wq,
                                               const float* __restrict__ Wk,
                                               const float* __restrict__ Wv,
                                               ushort_t* __restrict__ Wh,
                                               ushort_t* __restrict__ Wl) {
    int idx = (blockIdx.x * 256 + threadIdx.x) * 4;
#pragma unroll
    for (int e = 0; e < 4; e++) {
        int i = idx + e;
        int m = i >> 9, k = i & 511;
        float v = (m < C_Q) ? Wq[m * C_IN + k]
                 : (m < 2 * C_Q) ? Wk[(m - C_Q) * C_IN + k]
                 : (m < M_Y) ? Wv[(size_t)(m - 2 * C_Q) * C_IN + k]
                 : 0.f;                              // zero pad rows 640-767
        ushort_t h = f2h(v);
        Wh[i] = h;
        Wl[i] = f2h(v - h2f(h));
    }
}

// ---------------------------------------------------------------------------
// transpose + split: x [512][4096] fp32 -> xT hi/lo [4096][512] fp16
// blockIdx.z selects the batch.  Also zeroes this batch's D[4096].
// ---------------------------------------------------------------------------
__global__ __launch_bounds__(256) void split_x(const float* __restrict__ x,
                                               ushort_t* __restrict__ xTh,
                                               ushort_t* __restrict__ xTl,
                                               float* __restrict__ D) {
    const size_t bz = blockIdx.z;
    x   += bz * ((size_t)C_IN * HW_N);
    xTh += bz * ((size_t)HW_N * C_IN);
    xTl += bz * ((size_t)HW_N * C_IN);
    D   += bz * HW_N;

    if (blockIdx.y == 0 && blockIdx.x < 16) D[blockIdx.x * 256 + threadIdx.x] = 0.f;

    __shared__ float tile[64][65];
    const int n0 = blockIdx.x * 64, k0 = blockIdx.y * 64;
    const int t = threadIdx.x;
#pragma unroll
    for (int it = 0; it < 4; it++) {
        int e = t + it * 256;
        int r = e >> 4, c4 = (e & 15) << 2;
        float4 v = *(const float4*)(x + (size_t)(k0 + r) * HW_N + n0 + c4);
        tile[r][c4 + 0] = v.x; tile[r][c4 + 1] = v.y;
        tile[r][c4 + 2] = v.z; tile[r][c4 + 3] = v.w;
    }
    __syncthreads();
    const int rr = t >> 2, kq = (t & 3) << 4;
    ushort_t h[16], l[16];
#pragma unroll
    for (int j = 0; j < 16; j++) {
        float v = tile[kq + j][rr];
        h[j] = f2h(v);
        l[j] = f2h(v - h2f(h[j]));
    }
    size_t o = (size_t)(n0 + rr) * C_IN + k0 + kq;
    *(uint4*)(xTh + o) = *(uint4*)h;
    *(uint4*)(xTh + o + 8) = *(uint4*)(h + 8);
    *(uint4*)(xTl + o) = *(uint4*)l;
    *(uint4*)(xTl + o + 8) = *(uint4*)(l + 8);
}

// ---------------------------------------------------------------------------
// Y = W*x + b GEMM v3 (round-10 geometry, kept): 192m x 256n tile, 512
// threads = 8 waves (4m x 2n), wave-tile 48x128 (acc[3][8]).  192-row M
// tiles (M_YP = 768 = 4x192) give grid (16,4,NB) = 256 blocks = every CU
// busy (round-9's 256m tile left 64 CUs idle).  LDS 112 KB, 1 block/CU.
// Staging: A-side waves 6 chunks each, B-side 8.  Single-barrier
// double-buffered pipeline + swizzle (0 bank conflicts).
// Round-10 verified: dropped off top-5 (<= 84 us, was 91).
// ---------------------------------------------------------------------------
__global__ __launch_bounds__(512, 2) void ygemm(
    const ushort_t* __restrict__ Ah, const ushort_t* __restrict__ Al,
    const ushort_t* __restrict__ Bh, const ushort_t* __restrict__ Bl,
    const float* __restrict__ bq, const float* __restrict__ bk,
    const float* __restrict__ bv,
    ushort_t* __restrict__ qkTh, ushort_t* __restrict__ qkTl,
    ushort_t* __restrict__ Vh, ushort_t* __restrict__ Vl) {
    const size_t bz = blockIdx.z;
    Bh   += bz * ((size_t)HW_N * C_IN);
    Bl   += bz * ((size_t)HW_N * C_IN);
    qkTh += bz * ((size_t)HW_N * 2 * C_Q);
    qkTl += bz * ((size_t)HW_N * 2 * C_Q);
    Vh   += bz * ((size_t)C_IN * HW_N);
    Vl   += bz * ((size_t)C_IN * HW_N);

    __shared__ ushort_t sAh[2][192 * 32];
    __shared__ ushort_t sAl[2][192 * 32];
    __shared__ ushort_t sBh[2][256 * 32];
    __shared__ ushort_t sBl[2][256 * 32];

    const int tid = threadIdx.x, w = tid >> 6, lane = tid & 63;
    const int quad = lane >> 4, lr = lane & 15;
    const int m0 = blockIdx.y * 192, n0 = blockIdx.x * 256;

    // staging partition: waves 0-1 -> Ah (6 chunks each), 2-3 -> Al,
    // 4-5 -> Bh (8 each), 6-7 -> Bl.  chunk = 16 rows x 32 k x 2B = 1 KB.
    const int cr = lane >> 2, uv = lane & 3;
    const int kcol = (uv ^ ((cr >> 1) & 3)) << 3;   // pre-swizzled 16B k-unit
    const ushort_t* src;
    ushort_t* dst0;
    int rowBase, chunk0, bufStride;
    if (w < 4) {
        src = (w < 2) ? Ah : Al;
        dst0 = (w < 2) ? sAh[0] : sAl[0];
        rowBase = m0; chunk0 = (w & 1) * 6; bufStride = 192 * 32;
    } else {
        src = (w < 6) ? Bh : Bl;
        dst0 = (w < 6) ? sBh[0] : sBl[0];
        rowBase = n0; chunk0 = (w & 1) * 8; bufStride = 256 * 32;
    }
    const ushort_t* gk = src + (size_t)(rowBase + chunk0 * 16 + cr) * C_IN + kcol;
    ushort_t* dstw = dst0 + chunk0 * 512;

    const int wm = (w & 3) * 48, wn = (w >> 2) * 128;
    const int up = (quad ^ ((lr >> 1) & 3)) << 3;   // read-side swizzle

    float4v acc[3][8];
#pragma unroll
    for (int i = 0; i < 3; i++)
#pragma unroll
        for (int j = 0; j < 8; j++) acc[i][j] = (float4v){0.f, 0.f, 0.f, 0.f};

    // prologue: stage k-step 0 into buf 0
    if (w < 4) {
#pragma unroll
        for (int c = 0; c < 6; c++)
            gl2lds16(gk + (size_t)(c * 16) * C_IN, dstw + c * 512);
    } else {
#pragma unroll
        for (int c = 0; c < 8; c++)
            gl2lds16(gk + (size_t)(c * 16) * C_IN, dstw + c * 512);
    }
    __syncthreads();

    const int NSTEP = C_IN / 32;    // 16
    for (int it = 0; it < NSTEP; ++it) {
        const int cur = it & 1, nxt = cur ^ 1;

        // issue next k-step's loads first — they fly over the MFMA section
        if (it + 1 < NSTEP) {
            ushort_t* db = dstw + nxt * bufStride;
            const ushort_t* gn = gk + (it + 1) * 32;
            if (w < 4) {
#pragma unroll
                for (int c = 0; c < 6; c++)
                    gl2lds16(gn + (size_t)(c * 16) * C_IN, db + c * 512);
            } else {
#pragma unroll
                for (int c = 0; c < 8; c++)
                    gl2lds16(gn + (size_t)(c * 16) * C_IN, db + c * 512);
            }
        }

        // B fragments upfront (reused by all 3 i); A per-i
        short8 bh[8], bl[8];
#pragma unroll
        for (int j = 0; j < 8; j++) {
            const int row = wn + j * 16 + lr;
            bh[j] = *(const short8*)&sBh[cur][row * 32 + up];
            bl[j] = *(const short8*)&sBl[cur][row * 32 + up];
        }
#pragma unroll
        for (int i = 0; i < 3; i++) {
            const int row = wm + i * 16 + lr;
            short8 ah = *(const short8*)&sAh[cur][row * 32 + up];
            short8 al = *(const short8*)&sAl[cur][row * 32 + up];
#pragma unroll
            for (int j = 0; j < 8; j++)
                acc[i][j] = __builtin_amdgcn_mfma_f32_16x16x32_f16(ah, bh[j], acc[i][j], 0, 0, 0);
#pragma unroll
            for (int j = 0; j < 8; j++)
                acc[i][j] = __builtin_amdgcn_mfma_f32_16x16x32_f16(ah, bl[j], acc[i][j], 0, 0, 0);
#pragma unroll
            for (int j = 0; j < 8; j++)
                acc[i][j] = __builtin_amdgcn_mfma_f32_16x16x32_f16(al, bh[j], acc[i][j], 0, 0, 0);
        }
        __syncthreads();  // drains nxt's gl2lds (flew over MFMA); orders WAR
    }

    // epilogue: +bias, fp16 hi/lo split; m<128 -> qkT (transposed), else V;
    // padded rows (m >= 640) skipped.
#pragma unroll
    for (int i = 0; i < 3; i++)
#pragma unroll
        for (int j = 0; j < 8; j++)
#pragma unroll
            for (int r = 0; r < 4; r++) {
                const int m = m0 + wm + i * 16 + quad * 4 + r;
                if (m >= M_Y) continue;
                const int n = n0 + wn + j * 16 + lr;
                float bi = (m < C_Q) ? bq[m]
                          : (m < 2 * C_Q) ? bk[m - C_Q] : bv[m - 2 * C_Q];
                float v = acc[i][j][r] + bi;
                ushort_t h = f2h(v);
                ushort_t lo = f2h(v - h2f(h));
                if (m < 2 * C_Q) {
                    qkTh[(size_t)n * (2 * C_Q) + m] = h;
                    qkTl[(size_t)n * (2 * C_Q) + m] = lo;
                } else {
                    Vh[(size_t)(m - 2 * C_Q) * HW_N + n] = h;
                    Vl[(size_t)(m - 2 * C_Q) * HW_N + n] = lo;
                }
            }
}

// ---------------------------------------------------------------------------
// S = q^T k GEMM: S[m,n] = sum_k q[k,m]*k[k,n], 3-term fp16 hi/lo, K = 64.
// All of K fits in LDS at a 256x256 tile (128 KB): stage everything (16
// gl2lds/wave) -> ONE barrier -> 192 MFMA/wave uninterrupted -> exp/rowsum
// epilogue.  512 threads, 8 waves (4m x 2n), wave-tile 64x128.
// Grid (16,16) per batch = 256 blocks = 1 block/CU, write-bound regime.
// ---------------------------------------------------------------------------
__global__ __launch_bounds__(512, 2) void qkgemm(const ushort_t* __restrict__ qkTh_,
                                                 const ushort_t* __restrict__ qkTl_,
                                                 float* __restrict__ outF,
                                                 float* __restrict__ Dsum) {
    __shared__ ushort_t sAh[2][256 * 32];
    __shared__ ushort_t sAl[2][256 * 32];
    __shared__ ushort_t sBh[2][256 * 32];
    __shared__ ushort_t sBl[2][256 * 32];

    const int tid = threadIdx.x, w = tid >> 6, lane = tid & 63;
    const int quad = lane >> 4, lr = lane & 15;
    const int m0 = blockIdx.y * 256, n0 = blockIdx.x * 256;

    // staging: wave w owns panel (mat = w>>1, ks = w&1); 16 chunks of
    // 16 rows x 64B.  mat: 0=q-hi, 1=q-lo, 2=k-hi, 3=k-lo.
    const int mat = w >> 1, ks = w & 1;
    const ushort_t* src = ((mat & 1) ? qkTl_ : qkTh_) + ((mat >> 1) ? C_Q : 0);
    ushort_t* dst0 = ((mat == 0) ? sAh : (mat == 1) ? sAl
                    : (mat == 2) ? sBh : sBl)[ks];
    const int rowBase = (mat >> 1) ? n0 : m0;
    const int cr = lane >> 2, uv = lane & 3;
    const int kcol = (uv ^ ((cr >> 1) & 3)) << 3;   // pre-swizzled 16B k-unit
    const ushort_t* gk = src + (size_t)(rowBase + cr) * (2 * C_Q) + ks * 32 + kcol;

    const int wm = (w & 3) * 64, wn = (w >> 2) * 128;
    const int up = (quad ^ ((lr >> 1) & 3)) << 3;   // read-side swizzle

    // stage the ENTIRE K range, one barrier
#pragma unroll
    for (int c = 0; c < 16; c++)
        gl2lds16(gk + (size_t)(c * 16) * (2 * C_Q), dst0 + c * 512);

    float4v acc[4][8];
#pragma unroll
    for (int i = 0; i < 4; i++)
#pragma unroll
        for (int j = 0; j < 8; j++) acc[i][j] = (float4v){0.f, 0.f, 0.f, 0.f};

    __syncthreads();   // all panels resident

#pragma unroll
    for (int k2 = 0; k2 < 2; k2++) {
        short8 bh[8], bl[8];
#pragma unroll
        for (int j = 0; j < 8; j++) {
            const int row = wn + j * 16 + lr;
            bh[j] = *(const short8*)&sBh[k2][row * 32 + up];
            bl[j] = *(const short8*)&sBl[k2][row * 32 + up];
        }
#pragma unroll
        for (int i = 0; i < 4; i++) {
            const int row = wm + i * 16 + lr;
            short8 ah = *(const short8*)&sAh[k2][row * 32 + up];
            short8 al = *(const short8*)&sAl[k2][row * 32 + up];
#pragma unroll
            for (int j = 0; j < 8; j++)
                acc[i][j] = __builtin_amdgcn_mfma_f32_16x16x32_f16(ah, bh[j], acc[i][j], 0, 0, 0);
#pragma unroll
            for (int j = 0; j < 8; j++)
                acc[i][j] = __builtin_amdgcn_mfma_f32_16x16x32_f16(ah, bl[j], acc[i][j], 0, 0, 0);
#pragma unroll
            for (int j = 0; j < 8; j++)
                acc[i][j] = __builtin_amdgcn_mfma_f32_16x16x32_f16(al, bh[j], acc[i][j], 0, 0, 0);
        }
    }

    // epilogue: store S + fused per-row exp-sum partials
#pragma unroll
    for (int i = 0; i < 4; i++) {
#pragma unroll
        for (int r = 0; r < 4; r++) {
            float s = 0.f;
#pragma unroll
            for (int j = 0; j < 8; j++) {
                const int m = m0 + wm + i * 16 + quad * 4 + r;
                const int n = n0 + wn + j * 16 + lr;
                outF[(size_t)m * HW_N + n] = acc[i][j][r];
                s += __expf(acc[i][j][r]);
            }
            s += __shfl_xor(s, 1);
            s += __shfl_xor(s, 2);
            s += __shfl_xor(s, 4);
            s += __shfl_xor(s, 8);
            if (lr == 0)
                atomicAdd(&Dsum[m0 + wm + i * 16 + quad * 4 + r], s);
        }
    }
}

// ---------------------------------------------------------------------------
// feat GEMM v4.1 (round-8 exact, reverted from atomics): res[m,n] =
//   sum_k (Vh+Vl)[m,k] * P[n,k], P[n,k] = f16(exp2(S*log2e - log2 D[n])).
// Round-10 PMC: the fp32-atomic epilogue (feat8) ran 84.6 us vs 46.2 here
// — global_atomic_add_f32 is an L2 RMW per 4B, ~2x slower than coalesced
// dwordx4 plane stores + a separate reduce.  Reverted.
// 256m x 256n tile, 512 threads = 8 waves (4m x 2n), wave-tile 64x128.
// Convert runs AFTER the barrier on it+1's S (2-iter prefetch distance);
// B-fragment reads before the convert so their latency hides under it.
// LDS 96 KB, 1 block/CU, grid (16,2,8); z=8 k-split partials.
// ---------------------------------------------------------------------------
__global__ __launch_bounds__(512, 2) void feat7(const ushort_t* __restrict__ Vh,
                                                const ushort_t* __restrict__ Vl,
                                                const float* __restrict__ S,
                                                const float* __restrict__ D,
                                                float* __restrict__ out,
                                                float* __restrict__ part,
                                                int kLen) {
    __shared__ ushort_t sVh[2][256 * 32];
    __shared__ ushort_t sVl[2][256 * 32];
    __shared__ ushort_t sP [2][256 * 32];

    const int tid = threadIdx.x, w = tid >> 6, lane = tid & 63;
    const int quad = lane >> 4, lr = lane & 15;
    const int m0 = blockIdx.y * 256, n0 = blockIdx.x * 256;
    const int k0 = blockIdx.z * kLen;

    // V staging: waves 0-3 -> Vh chunks (w&3)*4..+3, waves 4-7 -> Vl ditto.
    const int crv = lane >> 2, uv = lane & 3;
    const int vcol = (uv ^ ((crv >> 1) & 3)) << 3;   // swizzled 16B unit
    const ushort_t* vbase = (w < 4) ? Vh : Vl;
    const ushort_t* gVsrc[4];
    int sOfs[4];
#pragma unroll
    for (int c = 0; c < 4; c++) {
        const int chunk = ((w & 3) * 4 + c);         // 0..15 within h or l
        gVsrc[c] = vbase + (size_t)(m0 + chunk * 16 + crv) * HW_N + vcol + k0;
        sOfs[c] = chunk * 512;
    }

    // S prefetch: thread owns rows pr+64c (c=0..3), 4-float k-unit pu.
    const int pr = tid >> 3, pu = tid & 7;
    const float* gS = S + (size_t)(n0 + pr) * HW_N + k0 + pu * 4;
    const int pdst = (((pu >> 1) ^ ((pr >> 1) & 3)) << 3) + ((pu & 1) << 2);
    float lrw[4];
#pragma unroll
    for (int c = 0; c < 4; c++) lrw[c] = -log2f(D[n0 + pr + 64 * c]);

    const int wm = (w & 3) * 64, wn = (w >> 2) * 128;

    float4 sreg[4];
    const int nIter = kLen >> 5;

    // prologue: load S(0), convert -> sP[0], prefetch S(1), stage V(0)
    {
#pragma unroll
        for (int c = 0; c < 4; c++)
            sreg[c] = *(const float4*)(gS + (size_t)(64 * c) * HW_N);
#pragma unroll
        for (int c = 0; c < 4; c++) gl2lds16(gVsrc[c], ((w < 4) ? sVh : sVl)[0] + sOfs[c]);
#pragma unroll
        for (int c = 0; c < 4; c++) {
            ushort_t h4[4];
            h4[0] = f2h(exp2f(fmaf(sreg[c].x, LOG2E, lrw[c])));
            h4[1] = f2h(exp2f(fmaf(sreg[c].y, LOG2E, lrw[c])));
            h4[2] = f2h(exp2f(fmaf(sreg[c].z, LOG2E, lrw[c])));
            h4[3] = f2h(exp2f(fmaf(sreg[c].w, LOG2E, lrw[c])));
            *(short4v*)&sP[0][(pr + 64 * c) * 32 + pdst] = *(short4v*)h4;
        }
        if (nIter > 1) {
#pragma unroll
            for (int c = 0; c < 4; c++)
                sreg[c] = *(const float4*)(gS + (size_t)(64 * c) * HW_N + 32);
        }
    }
    __syncthreads();  // V(0) + sP[0] visible

    float4v acc[4][8];
#pragma unroll
    for (int i = 0; i < 4; i++)
#pragma unroll
        for (int j = 0; j < 8; j++) acc[i][j] = (float4v){0.f, 0.f, 0.f, 0.f};

    for (int it = 0; it < nIter; ++it) {
        const int kk = it << 5;
        const int cur = it & 1, nxt = cur ^ 1;

        // issue next V tile first — flies through the whole MFMA section
        if (it + 1 < nIter) {
            ushort_t* db = ((w < 4) ? sVh : sVl)[nxt];
#pragma unroll
            for (int c = 0; c < 4; c++) gl2lds16(gVsrc[c] + kk + 32, db + sOfs[c]);
        }

        // B fragments FIRST: their ds_read latency hides under the convert
        short8 bh[8];
#pragma unroll
        for (int j = 0; j < 8; j++) {
            const int row = wn + j * 16 + lr;
            bh[j] = *(const short8*)&sP[cur][row * 32 + ((quad ^ ((lr >> 1) & 3)) << 3)];
        }

        // convert S(it+1) (in regs) -> sP[nxt]; overlaps other waves' MFMA.
        if (it + 1 < nIter) {
#pragma unroll
            for (int c = 0; c < 4; c++) {
                ushort_t h4[4];
                h4[0] = f2h(exp2f(fmaf(sreg[c].x, LOG2E, lrw[c])));
                h4[1] = f2h(exp2f(fmaf(sreg[c].y, LOG2E, lrw[c])));
                h4[2] = f2h(exp2f(fmaf(sreg[c].z, LOG2E, lrw[c])));
                h4[3] = f2h(exp2f(fmaf(sreg[c].w, LOG2E, lrw[c])));
                *(short4v*)&sP[nxt][(pr + 64 * c) * 32 + pdst] = *(short4v*)h4;
            }
            if (it + 2 < nIter) {
#pragma unroll
                for (int c = 0; c < 4; c++)
                    sreg[c] = *(const float4*)(gS + (size_t)(64 * c) * HW_N + kk + 64);
            }
        }

#pragma unroll
        for (int i = 0; i < 4; i++) {
            const int row = wm + i * 16 + lr;
            const int up = (quad ^ ((lr >> 1) & 3)) << 3;
            short8 ah = *(const short8*)&sVh[cur][row * 32 + up];
            short8 al = *(const short8*)&sVl[cur][row * 32 + up];
#pragma unroll
            for (int j = 0; j < 8; j++)
                acc[i][j] = __builtin_amdgcn_mfma_f32_16x16x32_f16(ah, bh[j], acc[i][j], 0, 0, 0);
#pragma unroll
            for (int j = 0; j < 8; j++)
                acc[i][j] = __builtin_amdgcn_mfma_f32_16x16x32_f16(al, bh[j], acc[i][j], 0, 0, 0);
        }
        __syncthreads();  // drains: vbuf[nxt] gl2lds, sP[nxt] writes; orders WAR
    }

    float* o = (blockIdx.z == 0) ? out
             : (part + (size_t)(blockIdx.z - 1) * ((size_t)C_IN * HW_N));
#pragma unroll
    for (int i = 0; i < 4; i++)
#pragma unroll
        for (int j = 0; j < 8; j++)
#pragma unroll
            for (int r = 0; r < 4; r++) {
                const int m = m0 + wm + i * 16 + quad * 4 + r;
                const int n = n0 + wn + j * 16 + lr;
                o[(size_t)m * HW_N + n] = acc[i][j][r];
            }
}

// out = alpha * (out + sum of np partials), float4-vectorized
__global__ __launch_bounds__(256) void reduce_alphaN(float* __restrict__ out,
                                                     const float4* __restrict__ part,
                                                     size_t stride4,
                                                     const float* __restrict__ alpha,
                                                     int np) {
    const size_t i = (size_t)blockIdx.x * 256 + threadIdx.x;
    const float a = alpha[0];
    float4* out4 = (float4*)out;
    float4 s = out4[i];
    for (int p = 0; p < np; p++) {
        float4 t = part[i + (size_t)p * stride4];
        s.x += t.x; s.y += t.y; s.z += t.z; s.w += t.w;
    }
    float4 o;
    o.x = a * s.x; o.y = a * s.y; o.z = a * s.z; o.w = a * s.w;
    out4[i] = o;
}

// ---------------------------------------------------------------------------

extern "C" void kernel_launch(void* const* d_in, const int* in_sizes, int n_in,
                              void* d_out, int out_size, void* d_ws, size_t ws_size,
                              hipStream_t stream) {
    const float* x     = (const float*)d_in[0];
    const float* Wq    = (const float*)d_in[1];
    const float* bq    = (const float*)d_in[2];
    const float* Wk    = (const float*)d_in[3];
    const float* bk    = (const float*)d_in[4];
    const float* Wv    = (const float*)d_in[5];
    const float* bv    = (const float*)d_in[6];
    const float* alpha = (const float*)d_in[7];
    float* out = (float*)d_out;

    const size_t planeQK = (size_t)HW_N * 2 * C_Q;   // qkT elems / batch
    const size_t planeV  = (size_t)C_IN * HW_N;      // V (and out) elems / batch
    const size_t planeXT = (size_t)HW_N * C_IN;      // xT elems / batch
    const size_t planeW  = (size_t)M_YP * C_IN;      // padded W
    const size_t planeS  = (size_t)HW_N * HW_N;

    // --- fused (4-batch) layout -------------------------------------------
    //   D4          : 4 x 4096 fp32
    //   qkTh4/qkTl4 : 4 x planeQK fp16 each        (8.4 MB)
    //   Vh4/Vl4     : 4 x planeV fp16 each         (33.6 MB)
    //   Wh/Wl       : planeW fp16 each             (1.6 MB, padded)
    //   scores      : planeS fp32                  (67.1 MB)
    //     overlay (dead after ygemm): xTh4/xTl4    (33.6 MB <= 67.1 OK)
    //   part        : 7 x planeV fp32              (58.7 MB)
    // total ~169 MB (known-satisfied: round-8 ran this fused layout)
    const size_t fusedBytes =
        (size_t)NB * HW_N * 4 + 2 * (size_t)NB * planeQK * 2 +
        2 * (size_t)NB * planeV * 2 + 2 * planeW * 2 + planeS * 4 +
        7 * planeV * 4;
    const bool fused = (ws_size >= fusedBytes);

    if (fused) {
        float* D4      = (float*)d_ws;
        ushort_t* qkTh4 = (ushort_t*)(D4 + (size_t)NB * HW_N);
        ushort_t* qkTl4 = qkTh4 + (size_t)NB * planeQK;
        ushort_t* Vh4   = qkTl4 + (size_t)NB * planeQK;
        ushort_t* Vl4   = Vh4 + (size_t)NB * planeV;
        ushort_t* Wh    = Vl4 + (size_t)NB * planeV;
        ushort_t* Wl    = Wh + planeW;
        float* scores   = (float*)(Wl + planeW);
        float* part     = scores + planeS;
        ushort_t* xTh4  = (ushort_t*)scores;           // overlay
        ushort_t* xTl4  = xTh4 + (size_t)NB * planeXT;

        split_w<<<dim3(M_YP * C_IN / 4 / 256), dim3(256), 0, stream>>>(Wq, Wk, Wv, Wh, Wl);

        // all 4 batches in one dispatch each
        split_x<<<dim3(HW_N / 64, C_IN / 64, NB), dim3(256), 0, stream>>>(
            x, xTh4, xTl4, D4);
        ygemm<<<dim3(HW_N / 256, M_YP / 192, NB), dim3(512), 0, stream>>>(
            Wh, Wl, xTh4, xTl4, bq, bk, bv, qkTh4, qkTl4, Vh4, Vl4);
        // (xT region dead from here on; scores may overwrite it)

        for (int b = 0; b < NB; b++) {
            float* outb = out + (size_t)b * planeV;
            qkgemm<<<dim3(HW_N / 256, HW_N / 256), dim3(512), 0, stream>>>(
                qkTh4 + (size_t)b * planeQK, qkTl4 + (size_t)b * planeQK,
                scores, D4 + (size_t)b * HW_N);
            feat7<<<dim3(HW_N / 256, C_IN / 256, 8), dim3(512), 0, stream>>>(
                Vh4 + (size_t)b * planeV, Vl4 + (size_t)b * planeV,
                scores, D4 + (size_t)b * HW_N, outb, part, HW_N / 8);
            reduce_alphaN<<<dim3((C_IN * HW_N / 4) / 256), dim3(256), 0, stream>>>(
                outb, (const float4*)part, planeV / 4, alpha, 7);
        }
        return;
    }

    // --- fallback: per-batch layout + loop -------------------------------
    float* D = (float*)d_ws;
    ushort_t* qkTh = (ushort_t*)(D + HW_N);
    ushort_t* qkTl = qkTh + planeQK;
    ushort_t* Vh   = qkTl + planeQK;
    ushort_t* Vl   = Vh + planeV;
    ushort_t* Wh   = Vl + planeV;
    ushort_t* Wl   = Wh + planeW;
    float* scores  = (float*)(Wl + planeW);
    float* part    = scores + planeS;
    ushort_t* xTh  = (ushort_t*)scores;
    ushort_t* xTl  = xTh + planeXT;

    const size_t baseF = (size_t)(part - (float*)d_ws);
    const int zsplit = (ws_size >= (baseF + 7 * planeV) * sizeof(float)) ? 8 : 4;

    split_w<<<dim3(M_YP * C_IN / 4 / 256), dim3(256), 0, stream>>>(Wq, Wk, Wv, Wh, Wl);

    for (int b = 0; b < NB; b++) {
        const float* xb = x + (size_t)b * planeV;
        float* outb = out + (size_t)b * planeV;

        split_x<<<dim3(HW_N / 64, C_IN / 64, 1), dim3(256), 0, stream>>>(
            xb, xTh, xTl, D);
        ygemm<<<dim3(HW_N / 256, M_YP / 192, 1), dim3(512), 0, stream>>>(
            Wh, Wl, xTh, xTl, bq, bk, bv, qkTh, qkTl, Vh, Vl);
        qkgemm<<<dim3(HW_N / 256, HW_N / 256), dim3(512), 0, stream>>>(
            qkTh, qkTl, scores, D);
        feat7<<<dim3(HW_N / 256, C_IN / 256, zsplit), dim3(512), 0, stream>>>(
            Vh, Vl, scores, D, outb, part, HW_N / zsplit);
        reduce_alphaN<<<dim3((C_IN * HW_N / 4) / 256), dim3(256), 0, stream>>>(
            outb, (const float4*)part, planeV / 4, alpha, zsplit - 1);
    }
}